// Round 1
// 641.795 us; speedup vs baseline: 1.0444x; 1.0444x over previous
//
#include <hip/hip_runtime.h>
#include <hip/hip_bf16.h>
#include <stdint.h>

// B=4, N=256, H=D=256.  M = N*N = 65536 edges per batch.
#define NB 4
#define NN 256
#define DD 256
#define MM 65536

typedef __attribute__((ext_vector_type(8))) __bf16 bf16x8;
typedef __attribute__((ext_vector_type(4))) __bf16 bf16x4;
typedef __attribute__((ext_vector_type(4))) float f32x4;

__device__ __forceinline__ f32x4 mfma_bf16(bf16x8 a, bf16x8 b, f32x4 c) {
    return __builtin_amdgcn_mfma_f32_16x16x32_bf16(a, b, c, 0, 0, 0);
}

// fragment-linear index for a [256 rows][256 cols] B-matrix:
// frag (nt,kk), lane (q,ln) holds row nt*16+ln, cols kk*32+q*8..+8
__device__ __forceinline__ size_t fragidx(int row, int col) {
    int nt = row >> 4, ln = row & 15;
    int kk = col >> 5, q = (col >> 3) & 3, e = col & 7;
    return ((size_t)((nt * 8 + kk) * 64 + q * 16 + ln)) * 8 + e;
}

// ---------------- tiny precompute kernels ----------------

__global__ void zero_kernel(float* __restrict__ p) {
    reinterpret_cast<float4*>(p)[blockIdx.x * 256 + threadIdx.x] =
        make_float4(0.f, 0.f, 0.f, 0.f);
}

// fused: k = hs@Wk + bk ; kqf[row,e] = (Wq[e,:].k)/16 (frag-linear) ; cb[row] = (bq.k)/16
__global__ void kkq_kernel(const float* __restrict__ hs, const float* __restrict__ Wk,
                           const float* __restrict__ bk, const float* __restrict__ Wq,
                           const float* __restrict__ bq, __bf16* __restrict__ kqf,
                           float* __restrict__ cb) {
    const int row = blockIdx.x, t = threadIdx.x;   // row in [0, NB*NN)
    __shared__ float hr[256];
    __shared__ float kr[256];
    __shared__ float red[256];
    hr[t] = hs[(size_t)row * 256 + t];
    __syncthreads();
    float v = bk[t];
    for (int e = 0; e < 256; ++e)
        v = fmaf(hr[e], Wk[(size_t)e * 256 + t], v);
    kr[t] = v;
    red[t] = v * bq[t];
    __syncthreads();
    float u = 0.f;
    for (int d = 0; d < 256; ++d)
        u = fmaf(Wq[(size_t)t * 256 + d], kr[d], u);
    const int b = row >> 8, n = row & 255;
    kqf[(size_t)b * NN * DD + fragidx(n, t)] = (__bf16)(u * 0.0625f);
    for (int s = 128; s > 0; s >>= 1) {
        if (t < s) red[t] += red[t + s];
        __syncthreads();
    }
    if (t == 0) cb[row] = red[0] * 0.0625f;
}

// wvof[h,e] = sum_d Wv[e,d]*Wo[d,h] (frag-linear, row=h) ; bvo[h] = bv.Wo[:,h]
__global__ void wvoprep_kernel(const float* __restrict__ Wv, const float* __restrict__ Wo,
                               const float* __restrict__ bv, __bf16* __restrict__ wvof,
                               float* __restrict__ bvo) {
    const int h = blockIdx.x, t = threadIdx.x;
    __shared__ float woc[256];
    __shared__ float red[256];
    float wo = Wo[(size_t)t * 256 + h];
    woc[t] = wo;
    red[t] = bv[t] * wo;
    __syncthreads();
    float v = 0.f;
    for (int d = 0; d < 256; ++d)
        v = fmaf(Wv[(size_t)t * 256 + d], woc[d], v);
    wvof[fragidx(h, t)] = (__bf16)v;
    for (int s = 128; s > 0; s >>= 1) {
        if (t < s) red[t] += red[t + s];
        __syncthreads();
    }
    if (t == 0) bvo[h] = red[0];
}

// ---------------- phase A (v2: 64 m-rows per wave, no LDS) ----------------
// PT (blocked [m/8][n][8]) = relu(scores)^T un-normalized;
// VOT (same layout)        = (inv[m] * vo[m][h])^T.
// One WG = 4 waves = 256 edge-rows; wave w owns rows [w*64, w*64+64).
// A-fragments for all 64 rows live in registers -> each B-fragment load
// (kqf/wvof, L2-resident) feeds 4 MFMAs. Outputs stored straight to global:
// per m-tile a wave's 64x8B stores form two contiguous 256B segments.
__global__ __launch_bounds__(256, 2)
void phaseA_kernel(const float* __restrict__ S, const __bf16* __restrict__ kqf,
                   const float* __restrict__ cb, const __bf16* __restrict__ wvof,
                   const float* __restrict__ bvo, const float* __restrict__ mask,
                   __bf16* __restrict__ PT, __bf16* __restrict__ VOT,
                   int c0, int CHS) {
    const int t = threadIdx.x;
    const int b = blockIdx.y;
    const int w = t >> 6;
    const int lane = t & 63;
    const int q = lane >> 4;
    const int ln = lane & 15;
    const int mloc = blockIdx.x * 256 + w * 64;   // wave's base within chunk
    const int m0 = c0 + mloc;                     // global edge base for wave

    // A-fragments: 64 rows (4 m-tiles) straight from global fp32, convert to bf16
    bf16x8 af[4][8];
#pragma unroll
    for (int mt = 0; mt < 4; ++mt) {
        const float* Ar = S + ((size_t)b * MM + m0 + mt * 16 + ln) * DD + q * 8;
#pragma unroll
        for (int kk = 0; kk < 8; ++kk) {
            float4 u0 = *reinterpret_cast<const float4*>(Ar + kk * 32);
            float4 u1 = *reinterpret_cast<const float4*>(Ar + kk * 32 + 4);
            af[mt][kk] = (bf16x8){(__bf16)u0.x, (__bf16)u0.y, (__bf16)u0.z, (__bf16)u0.w,
                                  (__bf16)u1.x, (__bf16)u1.y, (__bf16)u1.z, (__bf16)u1.w};
        }
    }

    // pairwise additive mask for this lane's 16 m-rows
    float m2[16];
#pragma unroll
    for (int mt = 0; mt < 4; ++mt)
#pragma unroll
        for (int r = 0; r < 4; ++r) {
            int mg = m0 + mt * 16 + q * 4 + r;
            m2[mt * 4 + r] = mask[b * NN + (mg >> 8)] * mask[b * NN + (mg & 255)];
        }

    float rs[16];
#pragma unroll
    for (int i = 0; i < 16; ++i) rs[i] = 0.f;

    const __bf16* kqb = kqf + (size_t)b * NN * DD + (size_t)lane * 8;
    const float* cbb = cb + b * NN + ln;
    __bf16* Pb = PT + (size_t)b * NN * CHS;
    __bf16* Vb = VOT + (size_t)b * NN * CHS;
    const int mb0 = mloc >> 3;                                  // local m-block base
    const size_t so = (size_t)ln * 8 + (size_t)(q & 1) * 4;     // lane store sub-offset

    // ---- scores GEMM: relu(S.kq^T/16 + cb + m2) -> PT (unnormalized), rowsums in rs
#pragma unroll 2
    for (int nt = 0; nt < 16; ++nt) {
        f32x4 a0 = {0.f, 0.f, 0.f, 0.f}, a1 = a0, a2 = a0, a3 = a0;
        const __bf16* kr = kqb + (size_t)nt * 4096;
#pragma unroll
        for (int kk = 0; kk < 8; ++kk) {
            bf16x8 bf = *reinterpret_cast<const bf16x8*>(kr + kk * 512);
            a0 = mfma_bf16(af[0][kk], bf, a0);
            a1 = mfma_bf16(af[1][kk], bf, a1);
            a2 = mfma_bf16(af[2][kk], bf, a2);
            a3 = mfma_bf16(af[3][kk], bf, a3);
        }
        const float cbv = cbb[nt * 16];
#define PROC_S(mt, A)                                                              \
        {                                                                          \
            float x0 = fmaxf(A.x + cbv + m2[mt * 4 + 0], 0.f);                     \
            float x1 = fmaxf(A.y + cbv + m2[mt * 4 + 1], 0.f);                     \
            float x2 = fmaxf(A.z + cbv + m2[mt * 4 + 2], 0.f);                     \
            float x3 = fmaxf(A.w + cbv + m2[mt * 4 + 3], 0.f);                     \
            rs[mt * 4 + 0] += x0; rs[mt * 4 + 1] += x1;                            \
            rs[mt * 4 + 2] += x2; rs[mt * 4 + 3] += x3;                            \
            bf16x4 pv = {(__bf16)x0, (__bf16)x1, (__bf16)x2, (__bf16)x3};          \
            *reinterpret_cast<bf16x4*>(Pb + (size_t)(mb0 + mt * 2 + (q >> 1)) * 2048 \
                                       + (size_t)nt * 128 + so) = pv;              \
        }
        PROC_S(0, a0) PROC_S(1, a1) PROC_S(2, a2) PROC_S(3, a3)
#undef PROC_S
    }

    // rowsum -> inverse (ref: probs / sum(probs + 1e-12) == probs / (rowsum + 256e-12))
#pragma unroll
    for (int i = 0; i < 16; ++i) {
        float v = rs[i];
        v += __shfl_xor(v, 1);
        v += __shfl_xor(v, 2);
        v += __shfl_xor(v, 4);
        v += __shfl_xor(v, 8);
        rs[i] = 1.f / (v + 2.56e-10f);
    }

    // ---- vo GEMM: (S.wvo^T + bvo) * inv[m] -> VOT
    const __bf16* wvb = wvof + (size_t)lane * 8;
#pragma unroll 2
    for (int nt = 0; nt < 16; ++nt) {
        f32x4 a0 = {0.f, 0.f, 0.f, 0.f}, a1 = a0, a2 = a0, a3 = a0;
        const __bf16* wr = wvb + (size_t)nt * 4096;
#pragma unroll
        for (int kk = 0; kk < 8; ++kk) {
            bf16x8 bf = *reinterpret_cast<const bf16x8*>(wr + kk * 512);
            a0 = mfma_bf16(af[0][kk], bf, a0);
            a1 = mfma_bf16(af[1][kk], bf, a1);
            a2 = mfma_bf16(af[2][kk], bf, a2);
            a3 = mfma_bf16(af[3][kk], bf, a3);
        }
        const float bb = bvo[nt * 16 + ln];
#define PROC_V(mt, A)                                                              \
        {                                                                          \
            bf16x4 pv = {(__bf16)((A.x + bb) * rs[mt * 4 + 0]),                    \
                         (__bf16)((A.y + bb) * rs[mt * 4 + 1]),                    \
                         (__bf16)((A.z + bb) * rs[mt * 4 + 2]),                    \
                         (__bf16)((A.w + bb) * rs[mt * 4 + 3])};                   \
            *reinterpret_cast<bf16x4*>(Vb + (size_t)(mb0 + mt * 2 + (q >> 1)) * 2048 \
                                       + (size_t)nt * 128 + so) = pv;              \
        }
        PROC_V(0, a0) PROC_V(1, a1) PROC_V(2, a2) PROC_V(3, a3)
#undef PROC_V
    }
}

// ---------------- phase B: out_acc[n,h] += P^T @ VO  (K = edge dim) ----------------
// Blocked layout makes every fragment load a coalesced 256-B segment; no LDS.
// Grid (4 nh-tiles, CHS/2048 K-chunks, NB). WG = 4 waves in 2x2; wave = 64x64.
__global__ __launch_bounds__(256, 2)
void phaseB_kernel(const __bf16* __restrict__ PT, const __bf16* __restrict__ VOT,
                   float* __restrict__ accg, int CHS) {
    const int t = threadIdx.x;
    const int b = blockIdx.z;
    const int w = t >> 6;
    const int lane = t & 63;
    const int q = lane >> 4;
    const int ln = lane & 15;
    const int n0 = (blockIdx.x >> 1) * 128 + (w >> 1) * 64;
    const int h0 = (blockIdx.x & 1) * 128 + (w & 1) * 64;
    const int g0 = blockIdx.y * 256;           // k-chunk of 2048 -> 256 blocks of 8

    f32x4 acc[16];
#pragma unroll
    for (int i = 0; i < 16; ++i) acc[i] = (f32x4){0.f, 0.f, 0.f, 0.f};

    const __bf16* Pb = PT + (size_t)b * NN * CHS;
    const __bf16* Vb = VOT + (size_t)b * NN * CHS;
#pragma unroll 2
    for (int ks = 0; ks < 64; ++ks) {
        const __bf16* Pk = Pb + ((size_t)(g0 + ks * 4 + q) * 256 + n0 + ln) * 8;
        const __bf16* Vk = Vb + ((size_t)(g0 + ks * 4 + q) * 256 + h0 + ln) * 8;
        bf16x8 a[4], bb[4];
#pragma unroll
        for (int i = 0; i < 4; ++i)
            a[i] = *reinterpret_cast<const bf16x8*>(Pk + i * 128);
#pragma unroll
        for (int j = 0; j < 4; ++j)
            bb[j] = *reinterpret_cast<const bf16x8*>(Vk + j * 128);
#pragma unroll
        for (int i = 0; i < 4; ++i)
#pragma unroll
            for (int j = 0; j < 4; ++j)
                acc[i * 4 + j] = mfma_bf16(a[i], bb[j], acc[i * 4 + j]);
    }
    float* og = accg + (size_t)b * NN * DD;
#pragma unroll
    for (int i = 0; i < 4; ++i)
#pragma unroll
        for (int j = 0; j < 4; ++j) {
            f32x4 a = acc[i * 4 + j];
            int n = n0 + i * 16 + q * 4;
            int h = h0 + j * 16 + ln;
            atomicAdd(&og[(size_t)(n + 0) * DD + h], a.x);
            atomicAdd(&og[(size_t)(n + 1) * DD + h], a.y);
            atomicAdd(&og[(size_t)(n + 2) * DD + h], a.z);
            atomicAdd(&og[(size_t)(n + 3) * DD + h], a.w);
        }
}

// ---------------- epilogue: +bo, +residual, LayerNorm ----------------
__global__ void epilogue_kernel(const float* __restrict__ accg, const float* __restrict__ hs,
                                const float* __restrict__ bo, const float* __restrict__ g,
                                const float* __restrict__ be, float* __restrict__ out) {
    const int row = blockIdx.x, t = threadIdx.x;
    __shared__ float red[256];
    const size_t base = (size_t)row * 256;
    float x = accg[base + t] + bo[t] + hs[base + t];
    red[t] = x;
    __syncthreads();
    for (int s = 128; s > 0; s >>= 1) {
        if (t < s) red[t] += red[t + s];
        __syncthreads();
    }
    float mean = red[0] * (1.f / 256.f);
    __syncthreads();
    float d = x - mean;
    red[t] = d * d;
    __syncthreads();
    for (int s = 128; s > 0; s >>= 1) {
        if (t < s) red[t] += red[t + s];
        __syncthreads();
    }
    float var = red[0] * (1.f / 256.f);
    out[base + t] = g[t] * d * rsqrtf(var + 1e-5f) + be[t];
}

// ---------------- host launch ----------------
extern "C" void kernel_launch(void* const* d_in, const int* in_sizes, int n_in,
                              void* d_out, int out_size, void* d_ws, size_t ws_size,
                              hipStream_t stream) {
    const float* hs   = (const float*)d_in[0];
    const float* S    = (const float*)d_in[1];
    const float* mask = (const float*)d_in[2];
    const float* Wq   = (const float*)d_in[3];
    const float* bq   = (const float*)d_in[4];
    const float* Wk   = (const float*)d_in[5];
    const float* bk   = (const float*)d_in[6];
    const float* Wv   = (const float*)d_in[7];
    const float* bv   = (const float*)d_in[8];
    const float* Wo   = (const float*)d_in[9];
    const float* bo   = (const float*)d_in[10];
    const float* g    = (const float*)d_in[11];
    const float* be   = (const float*)d_in[12];
    float* out = (float*)d_out;

    char* ws = (char*)d_ws;
    size_t off = 0;
    auto alloc = [&](size_t bytes) {
        void* p = ws + off;
        off += (bytes + 255) & ~(size_t)255;
        return p;
    };
    float*  accg = (float*)alloc((size_t)NB * NN * DD * 4);
    __bf16* kqf  = (__bf16*)alloc((size_t)NB * NN * DD * 2);
    float*  cb   = (float*)alloc((size_t)NB * NN * 4);
    __bf16* wvof = (__bf16*)alloc((size_t)NN * DD * 2);
    float*  bvo  = (float*)alloc((size_t)NN * 4);
    // largest per-batch edge-chunk that fits: PT+VOT = 2 * NB * CH * NN * 2 B
    size_t rem = ws_size > off ? ws_size - off : 0;
    int CH = MM;
    while (CH > 4096 && (size_t)CH * 4096 + 1024 > rem) CH >>= 1;
    __bf16* PT  = (__bf16*)alloc((size_t)NB * CH * NN * 2);
    __bf16* VOT = (__bf16*)alloc((size_t)NB * CH * NN * 2);

    zero_kernel<<<256, 256, 0, stream>>>(accg);
    kkq_kernel<<<NB * NN, 256, 0, stream>>>(hs, Wk, bk, Wq, bq, kqf, cb);
    wvoprep_kernel<<<NN, 256, 0, stream>>>(Wv, Wo, bv, wvof, bvo);
    for (int c0 = 0; c0 < MM; c0 += CH) {
        phaseA_kernel<<<dim3(CH / 256, NB), 256, 0, stream>>>(S, kqf, cb, wvof, bvo, mask,
                                                              PT, VOT, c0, CH);
        phaseB_kernel<<<dim3(4, CH / 2048, NB), 256, 0, stream>>>(PT, VOT, accg, CH);
    }
    epilogue_kernel<<<NB * NN, 256, 0, stream>>>(accg, hs, bo, g, be, out);
}